// Round 3
// baseline (89.858 us; speedup 1.0000x reference)
//
#include <hip/hip_runtime.h>
#include <hip/hip_bf16.h>

// out = relu(cos(x)*cos(theta) @ w1^T + b1) @ w2^T + b2
// B=16, S=4096 -> R=65536 rows; NQ=8; F=2048.
// Fully fused: one wave = 32 rows; both GEMMs on v_mfma_f32_32x32x16_bf16.
// GEMM1 computed transposed (C1 = W1' @ cosx^T) with W1 rows pre-permuted by
// swap(bit2,bit3) of the 32-slot index so C1's accum regs, after relu+pack,
// are directly GEMM2's B fragments (h^T). Bias b1 folded in as K-slot 8
// (B supplies 1.0 there); cos(theta) folded into W1. No inter-GEMM shuffles.

typedef __attribute__((ext_vector_type(8)))  short bhalf8;    // 8 bf16 (4 VGPR)
typedef __attribute__((ext_vector_type(16))) float floatx16;  // MFMA acc

// f32 -> bf16 round-to-nearest-even, bit-level (valid for finite values;
// avoids __hip_bfloat162 which is not trivially copyable for bit_cast).
__device__ __forceinline__ unsigned bf16_rn(float f) {
  unsigned u = __builtin_bit_cast(unsigned, f);
  return (u + 0x7fffu + ((u >> 16) & 1u)) >> 16;
}
__device__ __forceinline__ unsigned pk2(float a, float b) {
  return bf16_rn(a) | (bf16_rn(b) << 16);  // low 16 = bf16(a), high 16 = bf16(b)
}

__device__ __forceinline__ bhalf8 frag_from(unsigned a, unsigned b, unsigned c, unsigned d) {
  uint4 u = make_uint4(a, b, c, d);
  return __builtin_bit_cast(bhalf8, u);
}

#define W2_STRIDE 2056  // 2048 + 8 pad elems -> row stride 4112 B (bank offset 4/lane)

__global__ __launch_bounds__(512, 2) void ffq_kernel(
    const float* __restrict__ x, const float* __restrict__ theta,
    const float* __restrict__ w1, const float* __restrict__ b1,
    const float* __restrict__ w2, const float* __restrict__ b2,
    float* __restrict__ out)
{
  // w1s: [64 f-tiles][32 slots][16] bf16; k0..7 = w1[f][k]*cos(theta_k),
  //      k8 = b1[f], k9..15 = 0.  Row = 32B -> uniform 8-access/bank (optimal).
  __shared__ __align__(16) unsigned short w1s[64 * 32 * 16];  // 65536 B
  __shared__ __align__(16) unsigned short w2s[8 * W2_STRIDE]; // 32896 B

  const int tid = threadIdx.x;

  // ---------------- stage weights (once per block) ----------------
  float ct[8];
  #pragma unroll
  for (int k = 0; k < 8; ++k) ct[k] = cosf(theta[k]);

  for (int r = tid; r < 2048; r += 512) {          // r = t*32 + s
    int s = r & 31;
    // slot s holds f = tilebase + swap23(s)
    int f = (r & ~31) | (s & 19) | ((s & 4) << 1) | ((s & 8) >> 1);
    const float4* wp = (const float4*)(w1 + f * 8);
    float4 wa = wp[0], wb = wp[1];
    uint4 q;
    q.x = pk2(wa.x * ct[0], wa.y * ct[1]);
    q.y = pk2(wa.z * ct[2], wa.w * ct[3]);
    q.z = pk2(wb.x * ct[4], wb.y * ct[5]);
    q.w = pk2(wb.z * ct[6], wb.w * ct[7]);
    *(uint4*)&w1s[r * 16]     = q;
    *(uint4*)&w1s[r * 16 + 8] = make_uint4(pk2(b1[f], 0.0f), 0u, 0u, 0u);
  }
  for (int e = tid; e < 2048; e += 512) {          // 8 bf16 per thread-iter
    int c = e >> 8, n0 = (e & 255) * 8;
    const float4* wp = (const float4*)(w2 + c * 2048 + n0);
    float4 va = wp[0], vb = wp[1];
    uint4 q;
    q.x = pk2(va.x, va.y); q.y = pk2(va.z, va.w);
    q.z = pk2(vb.x, vb.y); q.w = pk2(vb.z, vb.w);
    *(uint4*)&w2s[c * W2_STRIDE + n0] = q;
  }
  __syncthreads();

  // ---------------- per-wave 32-row tile ----------------
  const int lane = tid & 63;
  const int col  = lane & 31;          // x-row within tile (GEMM B-col / C-col)
  const int hi   = lane >> 5;          // K-half selector
  const int tile = blockIdx.x * 8 + (tid >> 6);   // 256 blocks * 8 waves = 2048 tiles
  const long rowbase = (long)tile * 32;

  // B1 fragment: cos(x[row][0..7]) in k0..7 (hi=0); k8=1.0 for bias row (hi=1).
  bhalf8 bq;
  if (hi == 0) {
    const float4* xp = (const float4*)(x + (rowbase + col) * 8);
    float4 xa = xp[0], xb = xp[1];
    bq = frag_from(pk2(cosf(xa.x), cosf(xa.y)),
                   pk2(cosf(xa.z), cosf(xa.w)),
                   pk2(cosf(xb.x), cosf(xb.y)),
                   pk2(cosf(xb.z), cosf(xb.w)));
  } else {
    bq = frag_from(0x3F80u, 0u, 0u, 0u);  // bf16(1.0) at k=8, rest 0
  }

  floatx16 acc = {0.f,0.f,0.f,0.f,0.f,0.f,0.f,0.f,0.f,0.f,0.f,0.f,0.f,0.f,0.f,0.f};
  const floatx16 zf = acc;

  const unsigned short* w2p = &w2s[(col & 7) * W2_STRIDE];  // lanes >=8: dup rows (C rows 8..31 unused)

  #pragma unroll 4
  for (int t = 0; t < 64; ++t) {
    // GEMM1: C1[slot, row] = sum_k w1'[f(slot),k] * cosx[row,k]  (+bias via k=8)
    bhalf8 a1 = *(const bhalf8*)&w1s[(t * 32 + col) * 16 + hi * 8];
    floatx16 h = __builtin_amdgcn_mfma_f32_32x32x16_bf16(a1, bq, zf, 0, 0, 0);

    // relu + pack: regs 0..7 -> k-chunk0 (f = t*32 + hi*8 + b), 8..15 -> chunk1 (+16)
    bhalf8 hc0 = frag_from(pk2(fmaxf(h[0], 0.f),  fmaxf(h[1], 0.f)),
                           pk2(fmaxf(h[2], 0.f),  fmaxf(h[3], 0.f)),
                           pk2(fmaxf(h[4], 0.f),  fmaxf(h[5], 0.f)),
                           pk2(fmaxf(h[6], 0.f),  fmaxf(h[7], 0.f)));
    bhalf8 hc1 = frag_from(pk2(fmaxf(h[8], 0.f),  fmaxf(h[9], 0.f)),
                           pk2(fmaxf(h[10], 0.f), fmaxf(h[11], 0.f)),
                           pk2(fmaxf(h[12], 0.f), fmaxf(h[13], 0.f)),
                           pk2(fmaxf(h[14], 0.f), fmaxf(h[15], 0.f)));

    // GEMM2: out^T[q, row] += w2[q, f-chunk] * h^T[f-chunk, row]
    const unsigned short* wp = w2p + t * 32 + hi * 8;
    bhalf8 a2a = *(const bhalf8*)wp;          // chunk0: f = t*32 + hi*8 + b
    bhalf8 a2b = *(const bhalf8*)(wp + 16);   // chunk1: f = t*32 + 16 + hi*8 + b
    acc = __builtin_amdgcn_mfma_f32_32x32x16_bf16(a2a, hc0, acc, 0, 0, 0);
    acc = __builtin_amdgcn_mfma_f32_32x32x16_bf16(a2b, hc1, acc, 0, 0, 0);
  }

  // C2 regs 0..3 at (col, hi) = out[rowbase+col][4*hi + 0..3]; fully coalesced.
  float4 b2v = ((const float4*)b2)[hi];
  float4 o = make_float4(acc[0] + b2v.x, acc[1] + b2v.y,
                         acc[2] + b2v.z, acc[3] + b2v.w);
  *(float4*)(out + (rowbase + col) * 8 + hi * 4) = o;
}

extern "C" void kernel_launch(void* const* d_in, const int* in_sizes, int n_in,
                              void* d_out, int out_size, void* d_ws, size_t ws_size,
                              hipStream_t stream) {
  const float* x     = (const float*)d_in[0];
  const float* theta = (const float*)d_in[1];
  const float* w1    = (const float*)d_in[2];
  const float* b1    = (const float*)d_in[3];
  const float* w2    = (const float*)d_in[4];
  const float* b2    = (const float*)d_in[5];
  ffq_kernel<<<256, 512, 0, stream>>>(x, theta, w1, b1, w2, b2, (float*)d_out);
}

// Round 4
// 80.147 us; speedup vs baseline: 1.1212x; 1.1212x over previous
//
#include <hip/hip_runtime.h>
#include <hip/hip_bf16.h>

// out = relu(cos(x)*cos(theta) @ w1^T + b1) @ w2^T + b2
// B=16, S=4096 -> R=65536 rows; NQ=8; F=2048.
// Fully fused: one wave = 32 rows; both GEMMs on v_mfma_f32_32x32x16_bf16.
// GEMM1 computed transposed (C1 = W1' @ cosx^T) with W1 rows pre-permuted by
// swap(bit2,bit3) of the 32-slot index so C1's accum regs, after relu+pack,
// are directly GEMM2's B fragments (h^T). Bias b1 folded in as K-slot 8
// (B supplies 1.0 there); cos(theta) folded into W1. No inter-GEMM shuffles.
// R4 change: f32->bf16 pack via v_cvt_pk_bf16_f32 (1 inst / 2 elems) instead
// of 7-op bit-RTN sequence — kernel was VALU-bound on the pack.

typedef __attribute__((ext_vector_type(8)))  short bhalf8;    // 8 bf16 (4 VGPR)
typedef __attribute__((ext_vector_type(16))) float floatx16;  // MFMA acc

// pack 2 f32 -> 2 bf16 in one VALU op (low 16 = a, high 16 = b). No builtin
// on gfx950 (m240) -> inline asm. RNE rounding, same as reference-tolerant RTN.
__device__ __forceinline__ unsigned pk2(float a, float b) {
  unsigned r;
  asm("v_cvt_pk_bf16_f32 %0, %1, %2" : "=v"(r) : "v"(a), "v"(b));
  return r;
}

__device__ __forceinline__ bhalf8 frag_from(unsigned a, unsigned b, unsigned c, unsigned d) {
  uint4 u = make_uint4(a, b, c, d);
  return __builtin_bit_cast(bhalf8, u);
}

#define W2_STRIDE 2056  // 2048 + 8 pad elems -> row stride 4112 B (bank offset 4/lane)

__global__ __launch_bounds__(512, 2) void ffq_kernel(
    const float* __restrict__ x, const float* __restrict__ theta,
    const float* __restrict__ w1, const float* __restrict__ b1,
    const float* __restrict__ w2, const float* __restrict__ b2,
    float* __restrict__ out)
{
  // w1s: [64 f-tiles][32 slots][16] bf16; k0..7 = w1[f][k]*cos(theta_k),
  //      k8 = b1[f], k9..15 = 0.  Row = 32B -> uniform 8-access/bank (optimal).
  __shared__ __align__(16) unsigned short w1s[64 * 32 * 16];  // 65536 B
  __shared__ __align__(16) unsigned short w2s[8 * W2_STRIDE]; // 32896 B

  const int tid = threadIdx.x;

  // ---------------- stage weights (once per block) ----------------
  float ct[8];
  #pragma unroll
  for (int k = 0; k < 8; ++k) ct[k] = cosf(theta[k]);

  for (int r = tid; r < 2048; r += 512) {          // r = t*32 + s
    int s = r & 31;
    // slot s holds f = tilebase + swap23(s)
    int f = (r & ~31) | (s & 19) | ((s & 4) << 1) | ((s & 8) >> 1);
    const float4* wp = (const float4*)(w1 + f * 8);
    float4 wa = wp[0], wb = wp[1];
    uint4 q;
    q.x = pk2(wa.x * ct[0], wa.y * ct[1]);
    q.y = pk2(wa.z * ct[2], wa.w * ct[3]);
    q.z = pk2(wb.x * ct[4], wb.y * ct[5]);
    q.w = pk2(wb.z * ct[6], wb.w * ct[7]);
    *(uint4*)&w1s[r * 16]     = q;
    *(uint4*)&w1s[r * 16 + 8] = make_uint4(pk2(b1[f], 0.0f), 0u, 0u, 0u);
  }
  for (int e = tid; e < 2048; e += 512) {          // 8 bf16 per thread-iter
    int c = e >> 8, n0 = (e & 255) * 8;
    const float4* wp = (const float4*)(w2 + c * 2048 + n0);
    float4 va = wp[0], vb = wp[1];
    uint4 q;
    q.x = pk2(va.x, va.y); q.y = pk2(va.z, va.w);
    q.z = pk2(vb.x, vb.y); q.w = pk2(vb.z, vb.w);
    *(uint4*)&w2s[c * W2_STRIDE + n0] = q;
  }
  __syncthreads();

  // ---------------- per-wave 32-row tile ----------------
  const int lane = tid & 63;
  const int col  = lane & 31;          // x-row within tile (GEMM B-col / C-col)
  const int hi   = lane >> 5;          // K-half selector
  const int tile = blockIdx.x * 8 + (tid >> 6);   // 256 blocks * 8 waves = 2048 tiles
  const long rowbase = (long)tile * 32;

  // B1 fragment: cos(x[row][0..7]) in k0..7 (hi=0); k8=1.0 for bias row (hi=1).
  bhalf8 bq;
  if (hi == 0) {
    const float4* xp = (const float4*)(x + (rowbase + col) * 8);
    float4 xa = xp[0], xb = xp[1];
    bq = frag_from(pk2(cosf(xa.x), cosf(xa.y)),
                   pk2(cosf(xa.z), cosf(xa.w)),
                   pk2(cosf(xb.x), cosf(xb.y)),
                   pk2(cosf(xb.z), cosf(xb.w)));
  } else {
    bq = frag_from(0x3F80u, 0u, 0u, 0u);  // bf16(1.0) at k=8, rest 0
  }

  floatx16 acc = {0.f,0.f,0.f,0.f,0.f,0.f,0.f,0.f,0.f,0.f,0.f,0.f,0.f,0.f,0.f,0.f};
  const floatx16 zf = acc;

  const unsigned short* w2p = &w2s[(col & 7) * W2_STRIDE];  // lanes >=8: dup rows (C rows 8..31 unused)

  #pragma unroll 4
  for (int t = 0; t < 64; ++t) {
    // GEMM1: C1[slot, row] = sum_k w1'[f(slot),k] * cosx[row,k]  (+bias via k=8)
    bhalf8 a1 = *(const bhalf8*)&w1s[(t * 32 + col) * 16 + hi * 8];
    floatx16 h = __builtin_amdgcn_mfma_f32_32x32x16_bf16(a1, bq, zf, 0, 0, 0);

    // relu + pack: regs 0..7 -> k-chunk0 (f = t*32 + hi*8 + b), 8..15 -> chunk1 (+16)
    bhalf8 hc0 = frag_from(pk2(fmaxf(h[0], 0.f),  fmaxf(h[1], 0.f)),
                           pk2(fmaxf(h[2], 0.f),  fmaxf(h[3], 0.f)),
                           pk2(fmaxf(h[4], 0.f),  fmaxf(h[5], 0.f)),
                           pk2(fmaxf(h[6], 0.f),  fmaxf(h[7], 0.f)));
    bhalf8 hc1 = frag_from(pk2(fmaxf(h[8], 0.f),  fmaxf(h[9], 0.f)),
                           pk2(fmaxf(h[10], 0.f), fmaxf(h[11], 0.f)),
                           pk2(fmaxf(h[12], 0.f), fmaxf(h[13], 0.f)),
                           pk2(fmaxf(h[14], 0.f), fmaxf(h[15], 0.f)));

    // GEMM2: out^T[q, row] += w2[q, f-chunk] * h^T[f-chunk, row]
    const unsigned short* wp = w2p + t * 32 + hi * 8;
    bhalf8 a2a = *(const bhalf8*)wp;          // chunk0: f = t*32 + hi*8 + b
    bhalf8 a2b = *(const bhalf8*)(wp + 16);   // chunk1: f = t*32 + 16 + hi*8 + b
    acc = __builtin_amdgcn_mfma_f32_32x32x16_bf16(a2a, hc0, acc, 0, 0, 0);
    acc = __builtin_amdgcn_mfma_f32_32x32x16_bf16(a2b, hc1, acc, 0, 0, 0);
  }

  // C2 regs 0..3 at (col, hi) = out[rowbase+col][4*hi + 0..3]; fully coalesced.
  float4 b2v = ((const float4*)b2)[hi];
  float4 o = make_float4(acc[0] + b2v.x, acc[1] + b2v.y,
                         acc[2] + b2v.z, acc[3] + b2v.w);
  *(float4*)(out + (rowbase + col) * 8 + hi * 4) = o;
}

extern "C" void kernel_launch(void* const* d_in, const int* in_sizes, int n_in,
                              void* d_out, int out_size, void* d_ws, size_t ws_size,
                              hipStream_t stream) {
  const float* x     = (const float*)d_in[0];
  const float* theta = (const float*)d_in[1];
  const float* w1    = (const float*)d_in[2];
  const float* b1    = (const float*)d_in[3];
  const float* w2    = (const float*)d_in[4];
  const float* b2    = (const float*)d_in[5];
  ffq_kernel<<<256, 512, 0, stream>>>(x, theta, w1, b1, w2, b2, (float*)d_out);
}